// Round 1
// baseline (455.359 us; speedup 1.0000x reference)
//
#include <hip/hip_runtime.h>

#define B_ 8
#define H_ 128
#define W_ 256
#define C_ 128
#define D_ 128
#define PS 136   // p_lds row stride in shorts (272 B -> bank offset +4/row, 2-way max = free)

typedef __attribute__((ext_vector_type(4))) float f32x4;
typedef __attribute__((ext_vector_type(8))) short s16x8;
typedef __attribute__((ext_vector_type(4))) unsigned short u16x4;

__device__ __forceinline__ unsigned short f2bf(float f) {
    union { float f; unsigned u; } v; v.f = f;
    unsigned r = v.u + 0x7fffu + ((v.u >> 16) & 1u);   // RNE
    return (unsigned short)(r >> 16);
}
__device__ __forceinline__ float bf2f(unsigned short u) {
    union { unsigned u; float f; } v; v.u = ((unsigned)u) << 16; return v.f;
}
__device__ __forceinline__ float relu(float v) { return fmaxf(v, 0.f); }

// ---------------------------------------------------------------- K0
// c1x[b,i,w] = b1 + sum_{k,c} x[b,i,w+k-4,c]*w1[k,c]  (raw, pre-relu)
// s1[k] = sum_c w1[k,c];  w2t[d][c] = bf16(w2[0,4,c,d]); cs2[d] = sum_c w2[0,4,c,d]
// xb = bf16(x) (if enabled)
__global__ __launch_bounds__(256, 4) void k0_conv1(
    const float* __restrict__ x, const float* __restrict__ w1,
    const float* __restrict__ b1, const float* __restrict__ w2,
    float* __restrict__ c1x, float* __restrict__ s1,
    unsigned short* __restrict__ w2t, float* __restrict__ cs2,
    unsigned short* __restrict__ xb_out) {
    int bid = blockIdx.x, tid = threadIdx.x;
    if (bid >= B_ * H_) {                      // w2t staging blocks
        int idx = (bid - B_ * H_) * 256 + tid; // 0..16383
        int d = idx & (D_ - 1), c = idx >> 7;
        w2t[d * C_ + c] = f2bf(w2[4 * C_ * D_ + c * D_ + d]);
        if (bid == B_ * H_ && tid < D_) {      // cs2 column sums (fp32)
            float s = 0.f;
            for (int cc = 0; cc < C_; ++cc) s += w2[4 * C_ * D_ + cc * D_ + tid];
            cs2[tid] = s;
        }
        return;
    }
    if (bid == 0 && tid < 9) {
        float s = 0.f;
        for (int c = 0; c < C_; ++c) s += w1[tid * C_ + c];
        s1[tid] = s;
    }
    __shared__ float w1s[9 * C_];
    for (int t = tid; t < 9 * C_; t += 256) w1s[t] = w1[t];

    const float* xr = x + (size_t)bid * (W_ * C_);
    if (xb_out) {                              // bf16 copy of x (row-local, L2-hot)
        const f32x4* xr4 = (const f32x4*)xr;
        u16x4* xb4 = (u16x4*)(xb_out + (size_t)bid * (W_ * C_));
        for (int t = tid; t < (W_ * C_) / 4; t += 256) {
            f32x4 v = xr4[t];
            u16x4 o;
#pragma unroll
            for (int j = 0; j < 4; ++j) o[j] = f2bf(v[j]);
            xb4[t] = o;
        }
    }
    __syncthreads();

    int wv = tid >> 6, l = tid & 63;
    float w1a[9], w1b[9];
#pragma unroll
    for (int k = 0; k < 9; ++k) { w1a[k] = w1s[k * C_ + l]; w1b[k] = w1s[k * C_ + l + 64]; }
    float b1v = b1[0];

    for (int ch = 0; ch < 8; ++ch) {
        int p0 = wv * 64 + ch * 8;
        float part[8] = {0.f,0.f,0.f,0.f,0.f,0.f,0.f,0.f};
#pragma unroll
        for (int wr = 0; wr < 16; ++wr) {
            int wk = p0 + wr - 4;
            float v0 = 0.f, v1 = 0.f;
            if (wk >= 0 && wk < W_) { v0 = xr[wk * C_ + l]; v1 = xr[wk * C_ + l + 64]; }
#pragma unroll
            for (int pi = 0; pi < 8; ++pi) {
                int k = wr - pi;
                if (k >= 0 && k < 9) part[pi] += v0 * w1a[k] + v1 * w1b[k];
            }
        }
#pragma unroll
        for (int pi = 0; pi < 8; ++pi) {
            float v = part[pi];
#pragma unroll
            for (int off = 32; off > 0; off >>= 1) v += __shfl_down(v, off, 64);
            if (l == 0) c1x[(size_t)bid * W_ + p0 + pi] = v + b1v;
        }
    }
}

// ---------------------------------------------------------------- K12 (fused K1+K2)
// 512 threads / 8 waves per block: same 2 blocks/CU (LDS-limited) but 16 waves/CU
// = 4 waves/SIMD for latency hiding (was 2). Each wave owns M=32 output columns.
// sc[w] built from c1x; GEMM1: v = relu(x@W2 + sc*cs2 + b2)  [rank-1 sc fold]
// p[w+1] = x[w+1] + sc[w+1] + v[w] -> bf16 in LDS (q[W-1]=p[W-1] stored exact fp32)
// GEMM2 on LDS p; q[w] = r[w] + p[(w-1)&255] (w<=W-3); q[W-2] = r[W-1] + p[W-2]
__global__ __launch_bounds__(512, 4) void k12_fused(
    const float* __restrict__ x, const unsigned short* __restrict__ xb,
    const float* __restrict__ b2, const float* __restrict__ c1x_all,
    const float* __restrict__ s1, const unsigned short* __restrict__ w2t,
    const float* __restrict__ cs2, float* __restrict__ qout) {
    __shared__ unsigned short p_lds[W_ * PS];   // 69632 B
    __shared__ float sc[W_];                    // 1024 B
    int bid = blockIdx.x;            // row index b*H + i
    int b = bid >> 7, i = bid & 127;
    int tid = threadIdx.x;
    const float* c1 = c1x_all + (size_t)b * H_ * W_;

    int rowY;
    if (i == H_ - 1) rowY = H_ - 1;
    else if (i <= H_ - 3) rowY = (i - 1) & (H_ - 1);
    else rowY = H_ - 2;
    if (tid < W_) {  // phase 0: per-w scalar (verified in round 1)
        int w = tid;
        float scv;
        if (i == H_ - 1) {
            scv = relu(c1[(H_ - 2) * W_ + w]);
        } else {
            int iu = (i <= H_ - 3) ? i : (H_ - 1);
            float cu = c1[iu * W_ + w];
            if (iu >= 1) {
                const float* tp = c1 + (iu - 1) * W_;
#pragma unroll
                for (int k = 0; k < 9; ++k) {
                    int wk = w + k - 4;
                    if (wk >= 0 && wk < W_) cu += relu(tp[wk]) * s1[k];
                }
            }
            float tY = (rowY >= 1) ? relu(c1[(rowY - 1) * W_ + w]) : 0.f;
            scv = tY + relu(cu);
        }
        sc[w] = scv;
    }
    __syncthreads();

    const float* zrow = x + ((size_t)b * H_ + rowY) * (W_ * C_);
    const unsigned short* zb = xb ? xb + ((size_t)b * H_ + rowY) * (W_ * C_) : (const unsigned short*)0;
    float* qrow = qout + (size_t)bid * (W_ * C_);

    if (tid < C_) {                  // p[0] = z[0] = x[0] + sc[0]
        float z0 = (zb ? bf2f(zb[tid]) : zrow[tid]) + sc[0];
        p_lds[tid] = f2bf(z0);
    }

    int wv = tid >> 6, l = tid & 63, q = l >> 4, l15 = l & 15;
    int m0 = wv * 32;
    float b2v[8], cs2v[8];
#pragma unroll
    for (int nt = 0; nt < 8; ++nt) { int c = nt * 16 + l15; b2v[nt] = b2[c]; cs2v[nt] = cs2[c]; }

    f32x4 acc[2][8];
#pragma unroll
    for (int mt = 0; mt < 2; ++mt)
#pragma unroll
        for (int nt = 0; nt < 8; ++nt) acc[mt][nt] = (f32x4){0.f, 0.f, 0.f, 0.f};

    // ---- GEMM1: A = bf16(x row) (sc folded as rank-1 in epilogue)
#pragma unroll
    for (int kk = 0; kk < C_; kk += 32) {
        s16x8 af[2], bfr[8];
#pragma unroll
        for (int mt = 0; mt < 2; ++mt) {
            int w = m0 + mt * 16 + l15;
            if (zb) {
                af[mt] = *(const s16x8*)(zb + w * C_ + kk + q * 8);
            } else {
                const float* ap = zrow + w * C_ + kk + q * 8;
                f32x4 f0 = *(const f32x4*)ap;
                f32x4 f1 = *(const f32x4*)(ap + 4);
                s16x8 t;
#pragma unroll
                for (int j = 0; j < 4; ++j) t[j] = (short)f2bf(f0[j]);
#pragma unroll
                for (int j = 0; j < 4; ++j) t[4 + j] = (short)f2bf(f1[j]);
                af[mt] = t;
            }
        }
#pragma unroll
        for (int nt = 0; nt < 8; ++nt)
            bfr[nt] = *(const s16x8*)(w2t + (nt * 16 + l15) * C_ + kk + q * 8);
#pragma unroll
        for (int mt = 0; mt < 2; ++mt)
#pragma unroll
            for (int nt = 0; nt < 8; ++nt)
                acc[mt][nt] = __builtin_amdgcn_mfma_f32_16x16x32_bf16(af[mt], bfr[nt], acc[mt][nt], 0, 0, 0);
    }
    // ---- epilogue 1: p[w+1] = x[w+1] + sc[w+1] + v[w]  -> LDS bf16
#pragma unroll
    for (int nt = 0; nt < 8; ++nt) {
        int c = nt * 16 + l15;
#pragma unroll
        for (int mt = 0; mt < 2; ++mt) {
#pragma unroll
            for (int r = 0; r < 4; ++r) {
                int w = m0 + mt * 16 + q * 4 + r;
                float v = relu(acc[mt][nt][r] + sc[w] * cs2v[nt] + b2v[nt]);
                if (w < W_ - 1) {
                    float zv = zb ? bf2f(zb[(w + 1) * C_ + c]) : zrow[(w + 1) * C_ + c];
                    float p = zv + sc[w + 1] + v;
                    p_lds[(w + 1) * PS + c] = f2bf(p);
                    if (w == W_ - 2) qrow[(W_ - 1) * C_ + c] = p;   // q[W-1] = p[W-1], exact fp32
                }
            }
        }
    }
    __syncthreads();

    // ---- GEMM2: A = p (bf16, LDS)
#pragma unroll
    for (int mt = 0; mt < 2; ++mt)
#pragma unroll
        for (int nt = 0; nt < 8; ++nt) acc[mt][nt] = (f32x4){0.f, 0.f, 0.f, 0.f};
#pragma unroll
    for (int kk = 0; kk < C_; kk += 32) {
        s16x8 af[2], bfr[8];
#pragma unroll
        for (int mt = 0; mt < 2; ++mt) {
            int w = m0 + mt * 16 + l15;
            af[mt] = *(const s16x8*)(&p_lds[w * PS + kk + q * 8]);
        }
#pragma unroll
        for (int nt = 0; nt < 8; ++nt)
            bfr[nt] = *(const s16x8*)(w2t + (nt * 16 + l15) * C_ + kk + q * 8);
#pragma unroll
        for (int mt = 0; mt < 2; ++mt)
#pragma unroll
            for (int nt = 0; nt < 8; ++nt)
                acc[mt][nt] = __builtin_amdgcn_mfma_f32_16x16x32_bf16(af[mt], bfr[nt], acc[mt][nt], 0, 0, 0);
    }
    // ---- epilogue 2: q stores
#pragma unroll
    for (int nt = 0; nt < 8; ++nt) {
        int c = nt * 16 + l15;
#pragma unroll
        for (int mt = 0; mt < 2; ++mt) {
#pragma unroll
            for (int r = 0; r < 4; ++r) {
                int w = m0 + mt * 16 + q * 4 + r;
                if (w == W_ - 2) continue;       // r[W-2] unused; q[W-1] already stored
                float rr = relu(acc[mt][nt][r] + b2v[nt]);
                float pv = bf2f(p_lds[((w - 1) & (W_ - 1)) * PS + c]);
                int wd = (w <= W_ - 3) ? w : (W_ - 2);   // w==W-1 -> q[W-2] = r[W-1] + p[W-2]
                qrow[wd * C_ + c] = rr + pv;
            }
        }
    }
}

extern "C" void kernel_launch(void* const* d_in, const int* in_sizes, int n_in,
                              void* d_out, int out_size, void* d_ws, size_t ws_size,
                              hipStream_t stream) {
    const float* x  = (const float*)d_in[0];
    const float* w1 = (const float*)d_in[1];
    const float* b1 = (const float*)d_in[2];
    const float* w2 = (const float*)d_in[3];
    const float* b2 = (const float*)d_in[4];
    float* out = (float*)d_out;

    float* wsf = (float*)d_ws;
    // ws layout (floats): c1x[262144] | s1[16] | w2t[8192] | cs2[128] | xb[4194304]
    float* c1x = wsf;
    float* s1  = wsf + 262144;
    unsigned short* w2t = (unsigned short*)(wsf + 262160);
    float* cs2 = wsf + 270352;
    size_t need_bytes = ((size_t)270480 + 4194304) * 4;
    unsigned short* xb = (ws_size >= need_bytes) ? (unsigned short*)(wsf + 270480)
                                                 : (unsigned short*)0;

    k0_conv1<<<B_ * H_ + (C_ * D_) / 256, 256, 0, stream>>>(x, w1, b1, w2, c1x, s1, w2t, cs2, xb);
    k12_fused<<<B_ * H_, 512, 0, stream>>>(x, xb, b2, c1x, s1, w2t, cs2, out);
}

// Round 2
// 409.934 us; speedup vs baseline: 1.1108x; 1.1108x over previous
//
#include <hip/hip_runtime.h>

#define B_ 8
#define H_ 128
#define W_ 256
#define C_ 128
#define D_ 128
#define PS 136   // p_lds row stride in shorts (272 B -> bank offset +4/row, 2-way max = free)

typedef __attribute__((ext_vector_type(4))) float f32x4;
typedef __attribute__((ext_vector_type(8))) short s16x8;
typedef __attribute__((ext_vector_type(4))) unsigned short u16x4;

__device__ __forceinline__ unsigned short f2bf(float f) {
    union { float f; unsigned u; } v; v.f = f;
    unsigned r = v.u + 0x7fffu + ((v.u >> 16) & 1u);   // RNE
    return (unsigned short)(r >> 16);
}
__device__ __forceinline__ float bf2f(unsigned short u) {
    union { unsigned u; float f; } v; v.u = ((unsigned)u) << 16; return v.f;
}
__device__ __forceinline__ float relu(float v) { return fmaxf(v, 0.f); }

// ---------------------------------------------------------------- K0
// c1x[b,i,w] = b1 + sum_{k,c} x[b,i,w+k-4,c]*w1[k,c]  (raw, pre-relu)
// s1[k] = sum_c w1[k,c];  w2t[d][c] = bf16(w2[0,4,c,d]); cs2[d] = sum_c w2[0,4,c,d]
// xb = bf16(x) (if enabled)
__global__ __launch_bounds__(256, 4) void k0_conv1(
    const float* __restrict__ x, const float* __restrict__ w1,
    const float* __restrict__ b1, const float* __restrict__ w2,
    float* __restrict__ c1x, float* __restrict__ s1,
    unsigned short* __restrict__ w2t, float* __restrict__ cs2,
    unsigned short* __restrict__ xb_out) {
    int bid = blockIdx.x, tid = threadIdx.x;
    if (bid >= B_ * H_) {                      // w2t staging blocks
        int idx = (bid - B_ * H_) * 256 + tid; // 0..16383
        int d = idx & (D_ - 1), c = idx >> 7;
        w2t[d * C_ + c] = f2bf(w2[4 * C_ * D_ + c * D_ + d]);
        if (bid == B_ * H_ && tid < D_) {      // cs2 column sums (fp32)
            float s = 0.f;
            for (int cc = 0; cc < C_; ++cc) s += w2[4 * C_ * D_ + cc * D_ + tid];
            cs2[tid] = s;
        }
        return;
    }
    if (bid == 0 && tid < 9) {
        float s = 0.f;
        for (int c = 0; c < C_; ++c) s += w1[tid * C_ + c];
        s1[tid] = s;
    }
    __shared__ float w1s[9 * C_];
    for (int t = tid; t < 9 * C_; t += 256) w1s[t] = w1[t];

    const float* xr = x + (size_t)bid * (W_ * C_);
    if (xb_out) {                              // bf16 copy of x (row-local, L2-hot)
        const f32x4* xr4 = (const f32x4*)xr;
        u16x4* xb4 = (u16x4*)(xb_out + (size_t)bid * (W_ * C_));
        for (int t = tid; t < (W_ * C_) / 4; t += 256) {
            f32x4 v = xr4[t];
            u16x4 o;
#pragma unroll
            for (int j = 0; j < 4; ++j) o[j] = f2bf(v[j]);
            xb4[t] = o;
        }
    }
    __syncthreads();

    int wv = tid >> 6, l = tid & 63;
    float w1a[9], w1b[9];
#pragma unroll
    for (int k = 0; k < 9; ++k) { w1a[k] = w1s[k * C_ + l]; w1b[k] = w1s[k * C_ + l + 64]; }
    float b1v = b1[0];

    for (int ch = 0; ch < 8; ++ch) {
        int p0 = wv * 64 + ch * 8;
        float part[8] = {0.f,0.f,0.f,0.f,0.f,0.f,0.f,0.f};
#pragma unroll
        for (int wr = 0; wr < 16; ++wr) {
            int wk = p0 + wr - 4;
            float v0 = 0.f, v1 = 0.f;
            if (wk >= 0 && wk < W_) { v0 = xr[wk * C_ + l]; v1 = xr[wk * C_ + l + 64]; }
#pragma unroll
            for (int pi = 0; pi < 8; ++pi) {
                int k = wr - pi;
                if (k >= 0 && k < 9) part[pi] += v0 * w1a[k] + v1 * w1b[k];
            }
        }
#pragma unroll
        for (int pi = 0; pi < 8; ++pi) {
            float v = part[pi];
#pragma unroll
            for (int off = 32; off > 0; off >>= 1) v += __shfl_down(v, off, 64);
            if (l == 0) c1x[(size_t)bid * W_ + p0 + pi] = v + b1v;
        }
    }
}

// ---------------------------------------------------------------- K12 (fused K1+K2)
// 256 threads / 4 waves (round-0 config; 512-thr doubled HBM traffic -> reverted).
// OPERAND-SWAPPED MFMA: acc = mfma(B=w2t-frag, A=x/p-frag) so D is [d-row, w-col]:
// each thread holds ONE w and 4 CONSECUTIVE channels per fragment -> f32x4 stores,
// ds_read_b64/ds_write_b64 instead of 128 scalar LDS ops. Bit-identical math.
// sc[w] built from c1x; GEMM1: v = relu(x@W2 + sc*cs2 + b2)  [rank-1 sc fold]
// p[w+1] = x[w+1] + sc[w+1] + v[w] -> bf16 in LDS (q[W-1]=p[W-1] stored exact fp32)
// GEMM2 on LDS p; q[w] = r[w] + p[(w-1)&255] (w<=W-3); q[W-2] = r[W-1] + p[W-2]
__global__ __launch_bounds__(256, 2) void k12_fused(
    const float* __restrict__ x, const unsigned short* __restrict__ xb,
    const float* __restrict__ b2, const float* __restrict__ c1x_all,
    const float* __restrict__ s1, const unsigned short* __restrict__ w2t,
    const float* __restrict__ cs2, float* __restrict__ qout) {
    __shared__ unsigned short p_lds[W_ * PS];   // 69632 B
    __shared__ float sc[W_];                    // 1024 B
    int bid = blockIdx.x;            // row index b*H + i
    int b = bid >> 7, i = bid & 127;
    int tid = threadIdx.x;
    const float* c1 = c1x_all + (size_t)b * H_ * W_;

    int rowY;
    if (i == H_ - 1) rowY = H_ - 1;
    else if (i <= H_ - 3) rowY = (i - 1) & (H_ - 1);
    else rowY = H_ - 2;
    {   // phase 0: per-w scalar (verified in round 1)
        int w = tid;
        float scv;
        if (i == H_ - 1) {
            scv = relu(c1[(H_ - 2) * W_ + w]);
        } else {
            int iu = (i <= H_ - 3) ? i : (H_ - 1);
            float cu = c1[iu * W_ + w];
            if (iu >= 1) {
                const float* tp = c1 + (iu - 1) * W_;
#pragma unroll
                for (int k = 0; k < 9; ++k) {
                    int wk = w + k - 4;
                    if (wk >= 0 && wk < W_) cu += relu(tp[wk]) * s1[k];
                }
            }
            float tY = (rowY >= 1) ? relu(c1[(rowY - 1) * W_ + w]) : 0.f;
            scv = tY + relu(cu);
        }
        sc[w] = scv;
    }
    __syncthreads();

    const float* zrow = x + ((size_t)b * H_ + rowY) * (W_ * C_);
    const unsigned short* zb = xb ? xb + ((size_t)b * H_ + rowY) * (W_ * C_) : (const unsigned short*)0;
    float* qrow = qout + (size_t)bid * (W_ * C_);

    if (tid < C_) {                  // p[0] = z[0] = x[0] + sc[0]
        float z0 = (zb ? bf2f(zb[tid]) : zrow[tid]) + sc[0];
        p_lds[tid] = f2bf(z0);
    }

    int wv = tid >> 6, l = tid & 63, q = l >> 4, l15 = l & 15;
    int m0 = wv * 64;

    // epilogue constants: 4 consecutive channels per thread per nt
    f32x4 b2v4[8], cs2v4[8];
#pragma unroll
    for (int nt = 0; nt < 8; ++nt) {
        int d0 = nt * 16 + q * 4;
        b2v4[nt] = *(const f32x4*)(b2 + d0);
        cs2v4[nt] = *(const f32x4*)(cs2 + d0);
    }

    f32x4 acc[4][8];
#pragma unroll
    for (int mt = 0; mt < 4; ++mt)
#pragma unroll
        for (int nt = 0; nt < 8; ++nt) acc[mt][nt] = (f32x4){0.f, 0.f, 0.f, 0.f};

    // ---- GEMM1: A-op = w2t frag, B-op = bf16(x row) frag  (swapped -> D[d, w])
#pragma unroll
    for (int kk = 0; kk < C_; kk += 32) {
        s16x8 af[4], bfr[8];
#pragma unroll
        for (int mt = 0; mt < 4; ++mt) {
            int w = m0 + mt * 16 + l15;
            if (zb) {
                af[mt] = *(const s16x8*)(zb + w * C_ + kk + q * 8);
            } else {
                const float* ap = zrow + w * C_ + kk + q * 8;
                f32x4 f0 = *(const f32x4*)ap;
                f32x4 f1 = *(const f32x4*)(ap + 4);
                s16x8 t;
#pragma unroll
                for (int j = 0; j < 4; ++j) t[j] = (short)f2bf(f0[j]);
#pragma unroll
                for (int j = 0; j < 4; ++j) t[4 + j] = (short)f2bf(f1[j]);
                af[mt] = t;
            }
        }
#pragma unroll
        for (int nt = 0; nt < 8; ++nt)
            bfr[nt] = *(const s16x8*)(w2t + (nt * 16 + l15) * C_ + kk + q * 8);
#pragma unroll
        for (int mt = 0; mt < 4; ++mt)
#pragma unroll
            for (int nt = 0; nt < 8; ++nt)
                acc[mt][nt] = __builtin_amdgcn_mfma_f32_16x16x32_bf16(bfr[nt], af[mt], acc[mt][nt], 0, 0, 0);
    }
    // ---- epilogue 1: p[w+1] = x[w+1] + sc[w+1] + v[w]  -> LDS bf16 (vectorized)
    // thread holds w = m0+mt*16+l15 (one w per mt), channels d0..d0+3 per nt
#pragma unroll
    for (int mt = 0; mt < 4; ++mt) {
        int w = m0 + mt * 16 + l15;
        if (w < W_ - 1) {
            float scw = sc[w], scw1 = sc[w + 1];
#pragma unroll
            for (int nt = 0; nt < 8; ++nt) {
                int d0 = nt * 16 + q * 4;
                f32x4 zv;
                if (zb) {
                    u16x4 zv4 = *(const u16x4*)(zb + (w + 1) * C_ + d0);
#pragma unroll
                    for (int r = 0; r < 4; ++r) zv[r] = bf2f(zv4[r]);
                } else {
                    zv = *(const f32x4*)(zrow + (w + 1) * C_ + d0);
                }
                u16x4 pb;
                f32x4 pf;
#pragma unroll
                for (int r = 0; r < 4; ++r) {
                    float v = relu(acc[mt][nt][r] + scw * cs2v4[nt][r] + b2v4[nt][r]);
                    float p = zv[r] + scw1 + v;
                    pf[r] = p;
                    pb[r] = f2bf(p);
                }
                *(u16x4*)(&p_lds[(w + 1) * PS + d0]) = pb;       // ds_write_b64
                if (w == W_ - 2)                                  // q[W-1] = p[W-1], exact fp32
                    *(f32x4*)(qrow + (W_ - 1) * C_ + d0) = pf;
            }
        }
    }
    __syncthreads();

    // ---- GEMM2: A-op = w2t frag, B-op = p frag (bf16, LDS)
#pragma unroll
    for (int mt = 0; mt < 4; ++mt)
#pragma unroll
        for (int nt = 0; nt < 8; ++nt) acc[mt][nt] = (f32x4){0.f, 0.f, 0.f, 0.f};
#pragma unroll
    for (int kk = 0; kk < C_; kk += 32) {
        s16x8 af[4], bfr[8];
#pragma unroll
        for (int mt = 0; mt < 4; ++mt) {
            int w = m0 + mt * 16 + l15;
            af[mt] = *(const s16x8*)(&p_lds[w * PS + kk + q * 8]);
        }
#pragma unroll
        for (int nt = 0; nt < 8; ++nt)
            bfr[nt] = *(const s16x8*)(w2t + (nt * 16 + l15) * C_ + kk + q * 8);
#pragma unroll
        for (int mt = 0; mt < 4; ++mt)
#pragma unroll
            for (int nt = 0; nt < 8; ++nt)
                acc[mt][nt] = __builtin_amdgcn_mfma_f32_16x16x32_bf16(bfr[nt], af[mt], acc[mt][nt], 0, 0, 0);
    }
    // ---- epilogue 2: q stores (f32x4, coalesced 16B per lane)
#pragma unroll
    for (int mt = 0; mt < 4; ++mt) {
        int w = m0 + mt * 16 + l15;
        if (w == W_ - 2) continue;       // r[W-2] unused; q[W-1] already stored
        int wsrc = (w - 1) & (W_ - 1);
        int wd = (w <= W_ - 3) ? w : (W_ - 2);   // w==W-1 -> q[W-2] = r[W-1] + p[W-2]
#pragma unroll
        for (int nt = 0; nt < 8; ++nt) {
            int d0 = nt * 16 + q * 4;
            u16x4 pv4 = *(const u16x4*)(&p_lds[wsrc * PS + d0]);  // ds_read_b64
            f32x4 o;
#pragma unroll
            for (int r = 0; r < 4; ++r) {
                float rr = relu(acc[mt][nt][r] + b2v4[nt][r]);
                o[r] = rr + bf2f(pv4[r]);
            }
            *(f32x4*)(qrow + wd * C_ + d0) = o;
        }
    }
}

extern "C" void kernel_launch(void* const* d_in, const int* in_sizes, int n_in,
                              void* d_out, int out_size, void* d_ws, size_t ws_size,
                              hipStream_t stream) {
    const float* x  = (const float*)d_in[0];
    const float* w1 = (const float*)d_in[1];
    const float* b1 = (const float*)d_in[2];
    const float* w2 = (const float*)d_in[3];
    const float* b2 = (const float*)d_in[4];
    float* out = (float*)d_out;

    float* wsf = (float*)d_ws;
    // ws layout (floats): c1x[262144] | s1[16] | w2t[8192] | cs2[128] | xb[4194304]
    float* c1x = wsf;
    float* s1  = wsf + 262144;
    unsigned short* w2t = (unsigned short*)(wsf + 262160);
    float* cs2 = wsf + 270352;
    size_t need_bytes = ((size_t)270480 + 4194304) * 4;
    unsigned short* xb = (ws_size >= need_bytes) ? (unsigned short*)(wsf + 270480)
                                                 : (unsigned short*)0;

    k0_conv1<<<B_ * H_ + (C_ * D_) / 256, 256, 0, stream>>>(x, w1, b1, w2, c1x, s1, w2t, cs2, xb);
    k12_fused<<<B_ * H_, 256, 0, stream>>>(x, xb, b2, c1x, s1, w2t, cs2, out);
}

// Round 3
// 395.691 us; speedup vs baseline: 1.1508x; 1.0360x over previous
//
#include <hip/hip_runtime.h>

#define B_ 8
#define H_ 128
#define W_ 256
#define C_ 128
#define D_ 128
#define PS 136   // p_lds row stride in shorts (272 B -> bank offset +4/row, 2-way max = free)

typedef __attribute__((ext_vector_type(4))) float f32x4;
typedef __attribute__((ext_vector_type(8))) short s16x8;
typedef __attribute__((ext_vector_type(4))) unsigned short u16x4;

__device__ __forceinline__ unsigned short f2bf(float f) {
    union { float f; unsigned u; } v; v.f = f;
    unsigned r = v.u + 0x7fffu + ((v.u >> 16) & 1u);   // RNE
    return (unsigned short)(r >> 16);
}
__device__ __forceinline__ float bf2f(unsigned short u) {
    union { unsigned u; float f; } v; v.u = ((unsigned)u) << 16; return v.f;
}
__device__ __forceinline__ float relu(float v) { return fmaxf(v, 0.f); }

// ---------------------------------------------------------------- K0
// c1x[b,i,w] = b1 + sum_{k,c} x[b,i,w+k-4,c]*w1[k,c]  (raw, pre-relu)
// s1[k] = sum_c w1[k,c];  w2t[d][c] = bf16(w2[0,4,c,d]); cs2[d] = sum_c w2[0,4,c,d]
// xb = bf16(x) (if enabled)
__global__ __launch_bounds__(256, 4) void k0_conv1(
    const float* __restrict__ x, const float* __restrict__ w1,
    const float* __restrict__ b1, const float* __restrict__ w2,
    float* __restrict__ c1x, float* __restrict__ s1,
    unsigned short* __restrict__ w2t, float* __restrict__ cs2,
    unsigned short* __restrict__ xb_out) {
    int bid = blockIdx.x, tid = threadIdx.x;
    if (bid >= B_ * H_) {                      // w2t staging blocks
        int idx = (bid - B_ * H_) * 256 + tid; // 0..16383
        int d = idx & (D_ - 1), c = idx >> 7;
        w2t[d * C_ + c] = f2bf(w2[4 * C_ * D_ + c * D_ + d]);
        if (bid == B_ * H_ && tid < D_) {      // cs2 column sums (fp32)
            float s = 0.f;
            for (int cc = 0; cc < C_; ++cc) s += w2[4 * C_ * D_ + cc * D_ + tid];
            cs2[tid] = s;
        }
        return;
    }
    if (bid == 0 && tid < 9) {
        float s = 0.f;
        for (int c = 0; c < C_; ++c) s += w1[tid * C_ + c];
        s1[tid] = s;
    }
    __shared__ float w1s[9 * C_];
    for (int t = tid; t < 9 * C_; t += 256) w1s[t] = w1[t];

    const float* xr = x + (size_t)bid * (W_ * C_);
    if (xb_out) {                              // bf16 copy of x (row-local, L2-hot)
        const f32x4* xr4 = (const f32x4*)xr;
        u16x4* xb4 = (u16x4*)(xb_out + (size_t)bid * (W_ * C_));
        for (int t = tid; t < (W_ * C_) / 4; t += 256) {
            f32x4 v = xr4[t];
            u16x4 o;
#pragma unroll
            for (int j = 0; j < 4; ++j) o[j] = f2bf(v[j]);
            xb4[t] = o;
        }
    }
    __syncthreads();

    int wv = tid >> 6, l = tid & 63;
    float w1a[9], w1b[9];
#pragma unroll
    for (int k = 0; k < 9; ++k) { w1a[k] = w1s[k * C_ + l]; w1b[k] = w1s[k * C_ + l + 64]; }
    float b1v = b1[0];

    for (int ch = 0; ch < 8; ++ch) {
        int p0 = wv * 64 + ch * 8;
        float part[8] = {0.f,0.f,0.f,0.f,0.f,0.f,0.f,0.f};
#pragma unroll
        for (int wr = 0; wr < 16; ++wr) {
            int wk = p0 + wr - 4;
            float v0 = 0.f, v1 = 0.f;
            if (wk >= 0 && wk < W_) { v0 = xr[wk * C_ + l]; v1 = xr[wk * C_ + l + 64]; }
#pragma unroll
            for (int pi = 0; pi < 8; ++pi) {
                int k = wr - pi;
                if (k >= 0 && k < 9) part[pi] += v0 * w1a[k] + v1 * w1b[k];
            }
        }
#pragma unroll
        for (int pi = 0; pi < 8; ++pi) {
            float v = part[pi];
#pragma unroll
            for (int off = 32; off > 0; off >>= 1) v += __shfl_down(v, off, 64);
            if (l == 0) c1x[(size_t)bid * W_ + p0 + pi] = v + b1v;
        }
    }
}

// ---------------------------------------------------------------- K12 (fused K1+K2)
// Round-3 change: bulk async stage of the z-row (bf16) into p_lds via
// global_load_lds issued at kernel start, drained by the phase-0 barrier.
// z and p SHARE the LDS buffer (in-place same-thread update in epilogue-1;
// extra barrier after GEMM1 protects cross-wave z reads). Removes all
// per-fragment VMEM latency from GEMM1/epilogue-1 (was cross-XCD L2-miss,
// ~900cy exposed at 2 waves/SIMD). PS=136 pad kept: per-lane SOURCE address
// is pad-aware (row=P/272, off=P%272; pad lanes clamped, write into pad).
// Bit-identical math to round 2.
__global__ __launch_bounds__(256, 2) void k12_fused(
    const float* __restrict__ x, const unsigned short* __restrict__ xb,
    const float* __restrict__ b2, const float* __restrict__ c1x_all,
    const float* __restrict__ s1, const unsigned short* __restrict__ w2t,
    const float* __restrict__ cs2, float* __restrict__ qout) {
    __shared__ unsigned short p_lds[W_ * PS];   // 69632 B (z, then p, in place)
    __shared__ float sc[W_];                    // 1024 B
    int bid = blockIdx.x;            // row index b*H + i
    int b = bid >> 7, i = bid & 127;
    int tid = threadIdx.x;
    const float* c1 = c1x_all + (size_t)b * H_ * W_;

    int rowY;
    if (i == H_ - 1) rowY = H_ - 1;
    else if (i <= H_ - 3) rowY = (i - 1) & (H_ - 1);
    else rowY = H_ - 2;

    const float* zrow = x + ((size_t)b * H_ + rowY) * (W_ * C_);
    const unsigned short* zb = xb ? xb + ((size_t)b * H_ + rowY) * (W_ * C_) : (const unsigned short*)0;
    float* qrow = qout + (size_t)bid * (W_ * C_);

    // ---- phase -1: issue async z-row staging (68 KiB incl pad) FIRST.
    // Chunk ch covers p_lds bytes [ch*1024, ch*1024+1024): HW writes
    // wave-uniform base + lane*16. Source per-lane, pad-aware.
    if (zb) {
        const char* zbb = (const char*)zb;
        char* ldsb = (char*)p_lds;
        int l = tid & 63, wvv = tid >> 6;
#pragma unroll
        for (int it = 0; it < 17; ++it) {
            int chunk = it * 4 + wvv;            // 0..67 (68*1024 = 69632 B)
            int P = chunk * 1024 + l * 16;       // physical LDS byte this lane fills
            int row = P / 272;                   // 272 B per padded row
            int off = P - row * 272;             // 0..271; >=256 -> pad slot
            int soff = (off < 256) ? off : 0;    // pad lanes read row start (garbage ok)
            __builtin_amdgcn_global_load_lds(
                (const __attribute__((address_space(1))) void*)(zbb + row * 256 + soff),
                (__attribute__((address_space(3))) void*)(ldsb + chunk * 1024),
                16, 0, 0);
        }
    }

    {   // phase 0: per-w scalar sc (overlaps with staging latency)
        int w = tid;
        float scv;
        if (i == H_ - 1) {
            scv = relu(c1[(H_ - 2) * W_ + w]);
        } else {
            int iu = (i <= H_ - 3) ? i : (H_ - 1);
            float cu = c1[iu * W_ + w];
            if (iu >= 1) {
                const float* tp = c1 + (iu - 1) * W_;
#pragma unroll
                for (int k = 0; k < 9; ++k) {
                    int wk = w + k - 4;
                    if (wk >= 0 && wk < W_) cu += relu(tp[wk]) * s1[k];
                }
            }
            float tY = (rowY >= 1) ? relu(c1[(rowY - 1) * W_ + w]) : 0.f;
            scv = tY + relu(cu);
        }
        sc[w] = scv;
    }
    __syncthreads();   // drains vmcnt(0): staged z visible; sc visible

    int wv = tid >> 6, l = tid & 63, q = l >> 4, l15 = l & 15;
    int m0 = wv * 64;

    // epilogue constants: 4 consecutive channels per thread per nt
    f32x4 b2v4[8], cs2v4[8];
#pragma unroll
    for (int nt = 0; nt < 8; ++nt) {
        int d0 = nt * 16 + q * 4;
        b2v4[nt] = *(const f32x4*)(b2 + d0);
        cs2v4[nt] = *(const f32x4*)(cs2 + d0);
    }

    f32x4 acc[4][8];
#pragma unroll
    for (int mt = 0; mt < 4; ++mt)
#pragma unroll
        for (int nt = 0; nt < 8; ++nt) acc[mt][nt] = (f32x4){0.f, 0.f, 0.f, 0.f};

    // ---- GEMM1: A-op = w2t frag, B-op = z frag (bf16, from LDS)  -> D[d, w]
#pragma unroll
    for (int kk = 0; kk < C_; kk += 32) {
        s16x8 af[4], bfr[8];
#pragma unroll
        for (int mt = 0; mt < 4; ++mt) {
            int w = m0 + mt * 16 + l15;
            if (zb) {
                af[mt] = *(const s16x8*)(&p_lds[w * PS + kk + q * 8]);   // staged z
            } else {
                const float* ap = zrow + w * C_ + kk + q * 8;
                f32x4 f0 = *(const f32x4*)ap;
                f32x4 f1 = *(const f32x4*)(ap + 4);
                s16x8 t;
#pragma unroll
                for (int j = 0; j < 4; ++j) t[j] = (short)f2bf(f0[j]);
#pragma unroll
                for (int j = 0; j < 4; ++j) t[4 + j] = (short)f2bf(f1[j]);
                af[mt] = t;
            }
        }
#pragma unroll
        for (int nt = 0; nt < 8; ++nt)
            bfr[nt] = *(const s16x8*)(w2t + (nt * 16 + l15) * C_ + kk + q * 8);
#pragma unroll
        for (int mt = 0; mt < 4; ++mt)
#pragma unroll
            for (int nt = 0; nt < 8; ++nt)
                acc[mt][nt] = __builtin_amdgcn_mfma_f32_16x16x32_bf16(bfr[nt], af[mt], acc[mt][nt], 0, 0, 0);
    }
    __syncthreads();   // all waves done reading z before in-place p overwrite

    // ---- epilogue 1: p[w+1] = z[w+1] + sc[w+1] + v[w]  (in-place LDS update)
    // thread holds w = m0+mt*16+l15 (one w per mt), channels d0..d0+3 per nt;
    // the z[w+1,d0..d0+3] slot it reads is exactly the slot it overwrites.
#pragma unroll
    for (int mt = 0; mt < 4; ++mt) {
        int w = m0 + mt * 16 + l15;
        if (w < W_ - 1) {
            float scw = sc[w], scw1 = sc[w + 1];
#pragma unroll
            for (int nt = 0; nt < 8; ++nt) {
                int d0 = nt * 16 + q * 4;
                f32x4 zv;
                if (zb) {
                    u16x4 zv4 = *(const u16x4*)(&p_lds[(w + 1) * PS + d0]);
#pragma unroll
                    for (int r = 0; r < 4; ++r) zv[r] = bf2f(zv4[r]);
                } else {
                    zv = *(const f32x4*)(zrow + (w + 1) * C_ + d0);
                }
                u16x4 pb;
                f32x4 pf;
#pragma unroll
                for (int r = 0; r < 4; ++r) {
                    float v = relu(acc[mt][nt][r] + scw * cs2v4[nt][r] + b2v4[nt][r]);
                    float p = zv[r] + scw1 + v;
                    pf[r] = p;
                    pb[r] = f2bf(p);
                }
                *(u16x4*)(&p_lds[(w + 1) * PS + d0]) = pb;       // ds_write_b64
                if (w == W_ - 2)                                  // q[W-1] = p[W-1], exact fp32
                    *(f32x4*)(qrow + (W_ - 1) * C_ + d0) = pf;
            }
        }
    }
    // p[0] = z[0] + sc[0]: row 0 still holds z[0]; same-thread read-then-write
    if (tid < C_) {
        float z0 = zb ? bf2f(p_lds[tid]) : zrow[tid];
        p_lds[tid] = f2bf(z0 + sc[0]);
    }
    __syncthreads();

    // ---- GEMM2: A-op = w2t frag, B-op = p frag (bf16, LDS)
#pragma unroll
    for (int mt = 0; mt < 4; ++mt)
#pragma unroll
        for (int nt = 0; nt < 8; ++nt) acc[mt][nt] = (f32x4){0.f, 0.f, 0.f, 0.f};
#pragma unroll
    for (int kk = 0; kk < C_; kk += 32) {
        s16x8 af[4], bfr[8];
#pragma unroll
        for (int mt = 0; mt < 4; ++mt) {
            int w = m0 + mt * 16 + l15;
            af[mt] = *(const s16x8*)(&p_lds[w * PS + kk + q * 8]);
        }
#pragma unroll
        for (int nt = 0; nt < 8; ++nt)
            bfr[nt] = *(const s16x8*)(w2t + (nt * 16 + l15) * C_ + kk + q * 8);
#pragma unroll
        for (int mt = 0; mt < 4; ++mt)
#pragma unroll
            for (int nt = 0; nt < 8; ++nt)
                acc[mt][nt] = __builtin_amdgcn_mfma_f32_16x16x32_bf16(bfr[nt], af[mt], acc[mt][nt], 0, 0, 0);
    }
    // ---- epilogue 2: q stores (f32x4, coalesced 16B per lane)
#pragma unroll
    for (int mt = 0; mt < 4; ++mt) {
        int w = m0 + mt * 16 + l15;
        if (w == W_ - 2) continue;       // r[W-2] unused; q[W-1] already stored
        int wsrc = (w - 1) & (W_ - 1);
        int wd = (w <= W_ - 3) ? w : (W_ - 2);   // w==W-1 -> q[W-2] = r[W-1] + p[W-2]
#pragma unroll
        for (int nt = 0; nt < 8; ++nt) {
            int d0 = nt * 16 + q * 4;
            u16x4 pv4 = *(const u16x4*)(&p_lds[wsrc * PS + d0]);  // ds_read_b64
            f32x4 o;
#pragma unroll
            for (int r = 0; r < 4; ++r) {
                float rr = relu(acc[mt][nt][r] + b2v4[nt][r]);
                o[r] = rr + bf2f(pv4[r]);
            }
            *(f32x4*)(qrow + wd * C_ + d0) = o;
        }
    }
}

extern "C" void kernel_launch(void* const* d_in, const int* in_sizes, int n_in,
                              void* d_out, int out_size, void* d_ws, size_t ws_size,
                              hipStream_t stream) {
    const float* x  = (const float*)d_in[0];
    const float* w1 = (const float*)d_in[1];
    const float* b1 = (const float*)d_in[2];
    const float* w2 = (const float*)d_in[3];
    const float* b2 = (const float*)d_in[4];
    float* out = (float*)d_out;

    float* wsf = (float*)d_ws;
    // ws layout (floats): c1x[262144] | s1[16] | w2t[8192] | cs2[128] | xb[4194304]
    float* c1x = wsf;
    float* s1  = wsf + 262144;
    unsigned short* w2t = (unsigned short*)(wsf + 262160);
    float* cs2 = wsf + 270352;
    size_t need_bytes = ((size_t)270480 + 4194304) * 4;
    unsigned short* xb = (ws_size >= need_bytes) ? (unsigned short*)(wsf + 270480)
                                                 : (unsigned short*)0;

    k0_conv1<<<B_ * H_ + (C_ * D_) / 256, 256, 0, stream>>>(x, w1, b1, w2, c1x, s1, w2t, cs2, xb);
    k12_fused<<<B_ * H_, 256, 0, stream>>>(x, xb, b2, c1x, s1, w2t, cs2, out);
}

// Round 4
// 393.014 us; speedup vs baseline: 1.1586x; 1.0068x over previous
//
#include <hip/hip_runtime.h>

#define B_ 8
#define H_ 128
#define W_ 256
#define C_ 128
#define D_ 128
#define PS 136   // p_lds row stride in shorts (272 B -> bank offset +4/row, 2-way max = free)

typedef __attribute__((ext_vector_type(4))) float f32x4;
typedef __attribute__((ext_vector_type(8))) short s16x8;
typedef __attribute__((ext_vector_type(4))) unsigned short u16x4;

__device__ __forceinline__ unsigned short f2bf(float f) {
    union { float f; unsigned u; } v; v.f = f;
    unsigned r = v.u + 0x7fffu + ((v.u >> 16) & 1u);   // RNE
    return (unsigned short)(r >> 16);
}
__device__ __forceinline__ float bf2f(unsigned short u) {
    union { unsigned u; float f; } v; v.u = ((unsigned)u) << 16; return v.f;
}
__device__ __forceinline__ float relu(float v) { return fmaxf(v, 0.f); }
// Non-temporal f32x4 store: no L2 allocate -> qout (write-once) stops thrashing L2.
__device__ __forceinline__ void st_nt(float* p, f32x4 v) {
    __builtin_nontemporal_store(v, (f32x4*)p);
}

// ---------------------------------------------------------------- K0
// c1x[b,i,w] = b1 + sum_{k,c} x[b,i,w+k-4,c]*w1[k,c]  (raw, pre-relu)
// s1[k] = sum_c w1[k,c];  w2t[d][c] = bf16(w2[0,4,c,d]); cs2[d] = sum_c w2[0,4,c,d]
// xb = bf16(x) (if enabled)
__global__ __launch_bounds__(256, 4) void k0_conv1(
    const float* __restrict__ x, const float* __restrict__ w1,
    const float* __restrict__ b1, const float* __restrict__ w2,
    float* __restrict__ c1x, float* __restrict__ s1,
    unsigned short* __restrict__ w2t, float* __restrict__ cs2,
    unsigned short* __restrict__ xb_out) {
    int bid = blockIdx.x, tid = threadIdx.x;
    if (bid >= B_ * H_) {                      // w2t staging blocks
        int idx = (bid - B_ * H_) * 256 + tid; // 0..16383
        int d = idx & (D_ - 1), c = idx >> 7;
        w2t[d * C_ + c] = f2bf(w2[4 * C_ * D_ + c * D_ + d]);
        if (bid == B_ * H_ && tid < D_) {      // cs2 column sums (fp32)
            float s = 0.f;
            for (int cc = 0; cc < C_; ++cc) s += w2[4 * C_ * D_ + cc * D_ + tid];
            cs2[tid] = s;
        }
        return;
    }
    if (bid == 0 && tid < 9) {
        float s = 0.f;
        for (int c = 0; c < C_; ++c) s += w1[tid * C_ + c];
        s1[tid] = s;
    }
    __shared__ float w1s[9 * C_];
    for (int t = tid; t < 9 * C_; t += 256) w1s[t] = w1[t];

    const float* xr = x + (size_t)bid * (W_ * C_);
    if (xb_out) {                              // bf16 copy of x (row-local, L2-hot)
        const f32x4* xr4 = (const f32x4*)xr;
        u16x4* xb4 = (u16x4*)(xb_out + (size_t)bid * (W_ * C_));
        for (int t = tid; t < (W_ * C_) / 4; t += 256) {
            f32x4 v = xr4[t];
            u16x4 o;
#pragma unroll
            for (int j = 0; j < 4; ++j) o[j] = f2bf(v[j]);
            xb4[t] = o;
        }
    }
    __syncthreads();

    int wv = tid >> 6, l = tid & 63;
    float w1a[9], w1b[9];
#pragma unroll
    for (int k = 0; k < 9; ++k) { w1a[k] = w1s[k * C_ + l]; w1b[k] = w1s[k * C_ + l + 64]; }
    float b1v = b1[0];

    for (int ch = 0; ch < 8; ++ch) {
        int p0 = wv * 64 + ch * 8;
        float part[8] = {0.f,0.f,0.f,0.f,0.f,0.f,0.f,0.f};
#pragma unroll
        for (int wr = 0; wr < 16; ++wr) {
            int wk = p0 + wr - 4;
            float v0 = 0.f, v1 = 0.f;
            if (wk >= 0 && wk < W_) { v0 = xr[wk * C_ + l]; v1 = xr[wk * C_ + l + 64]; }
#pragma unroll
            for (int pi = 0; pi < 8; ++pi) {
                int k = wr - pi;
                if (k >= 0 && k < 9) part[pi] += v0 * w1a[k] + v1 * w1b[k];
            }
        }
#pragma unroll
        for (int pi = 0; pi < 8; ++pi) {
            float v = part[pi];
#pragma unroll
            for (int off = 32; off > 0; off >>= 1) v += __shfl_down(v, off, 64);
            if (l == 0) c1x[(size_t)bid * W_ + p0 + pi] = v + b1v;
        }
    }
}

// ---------------------------------------------------------------- K12 (fused K1+K2)
// Round-4 change: ALL qout stores are non-temporal (no L2 allocate). qout is
// write-once; allocating it thrashed the 4MB/XCD L2 (8MB concurrent output
// footprint per XCD) -> fetch-on-write + partial-dirty eviction churn was the
// suspected source of WRITE 352MB vs 134MB ideal. nt stores write fully-
// populated 64B sectors straight through, and stop evicting zb/w2t/c1x.
// Round-3 (kept): bulk async z-row staging into p_lds via global_load_lds,
// z and p share the buffer in place. Bit-identical math to rounds 2/3.
__global__ __launch_bounds__(256, 2) void k12_fused(
    const float* __restrict__ x, const unsigned short* __restrict__ xb,
    const float* __restrict__ b2, const float* __restrict__ c1x_all,
    const float* __restrict__ s1, const unsigned short* __restrict__ w2t,
    const float* __restrict__ cs2, float* __restrict__ qout) {
    __shared__ unsigned short p_lds[W_ * PS];   // 69632 B (z, then p, in place)
    __shared__ float sc[W_];                    // 1024 B
    int bid = blockIdx.x;            // row index b*H + i
    int b = bid >> 7, i = bid & 127;
    int tid = threadIdx.x;
    const float* c1 = c1x_all + (size_t)b * H_ * W_;

    int rowY;
    if (i == H_ - 1) rowY = H_ - 1;
    else if (i <= H_ - 3) rowY = (i - 1) & (H_ - 1);
    else rowY = H_ - 2;

    const float* zrow = x + ((size_t)b * H_ + rowY) * (W_ * C_);
    const unsigned short* zb = xb ? xb + ((size_t)b * H_ + rowY) * (W_ * C_) : (const unsigned short*)0;
    float* qrow = qout + (size_t)bid * (W_ * C_);

    // ---- phase -1: issue async z-row staging (68 KiB incl pad) FIRST.
    // Chunk ch covers p_lds bytes [ch*1024, ch*1024+1024): HW writes
    // wave-uniform base + lane*16. Source per-lane, pad-aware.
    if (zb) {
        const char* zbb = (const char*)zb;
        char* ldsb = (char*)p_lds;
        int l = tid & 63, wvv = tid >> 6;
#pragma unroll
        for (int it = 0; it < 17; ++it) {
            int chunk = it * 4 + wvv;            // 0..67 (68*1024 = 69632 B)
            int P = chunk * 1024 + l * 16;       // physical LDS byte this lane fills
            int row = P / 272;                   // 272 B per padded row
            int off = P - row * 272;             // 0..271; >=256 -> pad slot
            int soff = (off < 256) ? off : 0;    // pad lanes read row start (garbage ok)
            __builtin_amdgcn_global_load_lds(
                (const __attribute__((address_space(1))) void*)(zbb + row * 256 + soff),
                (__attribute__((address_space(3))) void*)(ldsb + chunk * 1024),
                16, 0, 0);
        }
    }

    {   // phase 0: per-w scalar sc (overlaps with staging latency)
        int w = tid;
        float scv;
        if (i == H_ - 1) {
            scv = relu(c1[(H_ - 2) * W_ + w]);
        } else {
            int iu = (i <= H_ - 3) ? i : (H_ - 1);
            float cu = c1[iu * W_ + w];
            if (iu >= 1) {
                const float* tp = c1 + (iu - 1) * W_;
#pragma unroll
                for (int k = 0; k < 9; ++k) {
                    int wk = w + k - 4;
                    if (wk >= 0 && wk < W_) cu += relu(tp[wk]) * s1[k];
                }
            }
            float tY = (rowY >= 1) ? relu(c1[(rowY - 1) * W_ + w]) : 0.f;
            scv = tY + relu(cu);
        }
        sc[w] = scv;
    }
    __syncthreads();   // drains vmcnt(0): staged z visible; sc visible

    int wv = tid >> 6, l = tid & 63, q = l >> 4, l15 = l & 15;
    int m0 = wv * 64;

    // epilogue constants: 4 consecutive channels per thread per nt
    f32x4 b2v4[8], cs2v4[8];
#pragma unroll
    for (int nt = 0; nt < 8; ++nt) {
        int d0 = nt * 16 + q * 4;
        b2v4[nt] = *(const f32x4*)(b2 + d0);
        cs2v4[nt] = *(const f32x4*)(cs2 + d0);
    }

    f32x4 acc[4][8];
#pragma unroll
    for (int mt = 0; mt < 4; ++mt)
#pragma unroll
        for (int nt = 0; nt < 8; ++nt) acc[mt][nt] = (f32x4){0.f, 0.f, 0.f, 0.f};

    // ---- GEMM1: A-op = w2t frag, B-op = z frag (bf16, from LDS)  -> D[d, w]
#pragma unroll
    for (int kk = 0; kk < C_; kk += 32) {
        s16x8 af[4], bfr[8];
#pragma unroll
        for (int mt = 0; mt < 4; ++mt) {
            int w = m0 + mt * 16 + l15;
            if (zb) {
                af[mt] = *(const s16x8*)(&p_lds[w * PS + kk + q * 8]);   // staged z
            } else {
                const float* ap = zrow + w * C_ + kk + q * 8;
                f32x4 f0 = *(const f32x4*)ap;
                f32x4 f1 = *(const f32x4*)(ap + 4);
                s16x8 t;
#pragma unroll
                for (int j = 0; j < 4; ++j) t[j] = (short)f2bf(f0[j]);
#pragma unroll
                for (int j = 0; j < 4; ++j) t[4 + j] = (short)f2bf(f1[j]);
                af[mt] = t;
            }
        }
#pragma unroll
        for (int nt = 0; nt < 8; ++nt)
            bfr[nt] = *(const s16x8*)(w2t + (nt * 16 + l15) * C_ + kk + q * 8);
#pragma unroll
        for (int mt = 0; mt < 4; ++mt)
#pragma unroll
            for (int nt = 0; nt < 8; ++nt)
                acc[mt][nt] = __builtin_amdgcn_mfma_f32_16x16x32_bf16(bfr[nt], af[mt], acc[mt][nt], 0, 0, 0);
    }
    __syncthreads();   // all waves done reading z before in-place p overwrite

    // ---- epilogue 1: p[w+1] = z[w+1] + sc[w+1] + v[w]  (in-place LDS update)
    // thread holds w = m0+mt*16+l15 (one w per mt), channels d0..d0+3 per nt;
    // the z[w+1,d0..d0+3] slot it reads is exactly the slot it overwrites.
#pragma unroll
    for (int mt = 0; mt < 4; ++mt) {
        int w = m0 + mt * 16 + l15;
        if (w < W_ - 1) {
            float scw = sc[w], scw1 = sc[w + 1];
#pragma unroll
            for (int nt = 0; nt < 8; ++nt) {
                int d0 = nt * 16 + q * 4;
                f32x4 zv;
                if (zb) {
                    u16x4 zv4 = *(const u16x4*)(&p_lds[(w + 1) * PS + d0]);
#pragma unroll
                    for (int r = 0; r < 4; ++r) zv[r] = bf2f(zv4[r]);
                } else {
                    zv = *(const f32x4*)(zrow + (w + 1) * C_ + d0);
                }
                u16x4 pb;
                f32x4 pf;
#pragma unroll
                for (int r = 0; r < 4; ++r) {
                    float v = relu(acc[mt][nt][r] + scw * cs2v4[nt][r] + b2v4[nt][r]);
                    float p = zv[r] + scw1 + v;
                    pf[r] = p;
                    pb[r] = f2bf(p);
                }
                *(u16x4*)(&p_lds[(w + 1) * PS + d0]) = pb;       // ds_write_b64
                if (w == W_ - 2)                                  // q[W-1] = p[W-1], exact fp32
                    st_nt(qrow + (W_ - 1) * C_ + d0, pf);
            }
        }
    }
    // p[0] = z[0] + sc[0]: row 0 still holds z[0]; same-thread read-then-write
    if (tid < C_) {
        float z0 = zb ? bf2f(p_lds[tid]) : zrow[tid];
        p_lds[tid] = f2bf(z0 + sc[0]);
    }
    __syncthreads();

    // ---- GEMM2: A-op = w2t frag, B-op = p frag (bf16, LDS)
#pragma unroll
    for (int mt = 0; mt < 4; ++mt)
#pragma unroll
        for (int nt = 0; nt < 8; ++nt) acc[mt][nt] = (f32x4){0.f, 0.f, 0.f, 0.f};
#pragma unroll
    for (int kk = 0; kk < C_; kk += 32) {
        s16x8 af[4], bfr[8];
#pragma unroll
        for (int mt = 0; mt < 4; ++mt) {
            int w = m0 + mt * 16 + l15;
            af[mt] = *(const s16x8*)(&p_lds[w * PS + kk + q * 8]);
        }
#pragma unroll
        for (int nt = 0; nt < 8; ++nt)
            bfr[nt] = *(const s16x8*)(w2t + (nt * 16 + l15) * C_ + kk + q * 8);
#pragma unroll
        for (int mt = 0; mt < 4; ++mt)
#pragma unroll
            for (int nt = 0; nt < 8; ++nt)
                acc[mt][nt] = __builtin_amdgcn_mfma_f32_16x16x32_bf16(bfr[nt], af[mt], acc[mt][nt], 0, 0, 0);
    }
    // ---- epilogue 2: q stores (non-temporal f32x4, 64B-sector aligned groups)
#pragma unroll
    for (int mt = 0; mt < 4; ++mt) {
        int w = m0 + mt * 16 + l15;
        if (w == W_ - 2) continue;       // r[W-2] unused; q[W-1] already stored
        int wsrc = (w - 1) & (W_ - 1);
        int wd = (w <= W_ - 3) ? w : (W_ - 2);   // w==W-1 -> q[W-2] = r[W-1] + p[W-2]
#pragma unroll
        for (int nt = 0; nt < 8; ++nt) {
            int d0 = nt * 16 + q * 4;
            u16x4 pv4 = *(const u16x4*)(&p_lds[wsrc * PS + d0]);  // ds_read_b64
            f32x4 o;
#pragma unroll
            for (int r = 0; r < 4; ++r) {
                float rr = relu(acc[mt][nt][r] + b2v4[nt][r]);
                o[r] = rr + bf2f(pv4[r]);
            }
            st_nt(qrow + wd * C_ + d0, o);
        }
    }
}

extern "C" void kernel_launch(void* const* d_in, const int* in_sizes, int n_in,
                              void* d_out, int out_size, void* d_ws, size_t ws_size,
                              hipStream_t stream) {
    const float* x  = (const float*)d_in[0];
    const float* w1 = (const float*)d_in[1];
    const float* b1 = (const float*)d_in[2];
    const float* w2 = (const float*)d_in[3];
    const float* b2 = (const float*)d_in[4];
    float* out = (float*)d_out;

    float* wsf = (float*)d_ws;
    // ws layout (floats): c1x[262144] | s1[16] | w2t[8192] | cs2[128] | xb[4194304]
    float* c1x = wsf;
    float* s1  = wsf + 262144;
    unsigned short* w2t = (unsigned short*)(wsf + 262160);
    float* cs2 = wsf + 270352;
    size_t need_bytes = ((size_t)270480 + 4194304) * 4;
    unsigned short* xb = (ws_size >= need_bytes) ? (unsigned short*)(wsf + 270480)
                                                 : (unsigned short*)0;

    k0_conv1<<<B_ * H_ + (C_ * D_) / 256, 256, 0, stream>>>(x, w1, b1, w2, c1x, s1, w2t, cs2, xb);
    k12_fused<<<B_ * H_, 256, 0, stream>>>(x, xb, b2, c1x, s1, w2t, cs2, out);
}

// Round 5
// 310.966 us; speedup vs baseline: 1.4643x; 1.2638x over previous
//
#include <hip/hip_runtime.h>

#define B_ 8
#define H_ 128
#define W_ 256
#define C_ 128
#define D_ 128
#define PS 136   // p_lds row stride in shorts (272 B -> bank offset +4/row, 2-way max = free)

typedef __attribute__((ext_vector_type(4))) float f32x4;
typedef __attribute__((ext_vector_type(8))) short s16x8;
typedef __attribute__((ext_vector_type(4))) unsigned short u16x4;

__device__ __forceinline__ unsigned short f2bf(float f) {
    union { float f; unsigned u; } v; v.f = f;
    unsigned r = v.u + 0x7fffu + ((v.u >> 16) & 1u);   // RNE
    return (unsigned short)(r >> 16);
}
__device__ __forceinline__ float bf2f(unsigned short u) {
    union { unsigned u; float f; } v; v.u = ((unsigned)u) << 16; return v.f;
}
__device__ __forceinline__ float relu(float v) { return fmaxf(v, 0.f); }

// ---------------------------------------------------------------- K0
// c1x[b,i,w] = b1 + sum_{k,c} x[b,i,w+k-4,c]*w1[k,c]  (raw, pre-relu)
// s1[k] = sum_c w1[k,c];  w2t[d][c] = bf16(w2[0,4,c,d]); cs2[d] = sum_c w2[0,4,c,d]
// Round-5: xb (bf16 copy of x) ELIMINATED — k12 reads x directly. k0 is now
// read-128MB / write-1MB.
__global__ __launch_bounds__(256, 4) void k0_conv1(
    const float* __restrict__ x, const float* __restrict__ w1,
    const float* __restrict__ b1, const float* __restrict__ w2,
    float* __restrict__ c1x, float* __restrict__ s1,
    unsigned short* __restrict__ w2t, float* __restrict__ cs2) {
    int bid = blockIdx.x, tid = threadIdx.x;
    if (bid >= B_ * H_) {                      // w2t staging blocks
        int idx = (bid - B_ * H_) * 256 + tid; // 0..16383
        int d = idx & (D_ - 1), c = idx >> 7;
        w2t[d * C_ + c] = f2bf(w2[4 * C_ * D_ + c * D_ + d]);
        if (bid == B_ * H_ && tid < D_) {      // cs2 column sums (fp32)
            float s = 0.f;
            for (int cc = 0; cc < C_; ++cc) s += w2[4 * C_ * D_ + cc * D_ + tid];
            cs2[tid] = s;
        }
        return;
    }
    if (bid == 0 && tid < 9) {
        float s = 0.f;
        for (int c = 0; c < C_; ++c) s += w1[tid * C_ + c];
        s1[tid] = s;
    }
    __shared__ float w1s[9 * C_];
    for (int t = tid; t < 9 * C_; t += 256) w1s[t] = w1[t];
    __syncthreads();

    const float* xr = x + (size_t)bid * (W_ * C_);
    int wv = tid >> 6, l = tid & 63;
    float w1a[9], w1b[9];
#pragma unroll
    for (int k = 0; k < 9; ++k) { w1a[k] = w1s[k * C_ + l]; w1b[k] = w1s[k * C_ + l + 64]; }
    float b1v = b1[0];

    for (int ch = 0; ch < 8; ++ch) {
        int p0 = wv * 64 + ch * 8;
        float part[8] = {0.f,0.f,0.f,0.f,0.f,0.f,0.f,0.f};
#pragma unroll
        for (int wr = 0; wr < 16; ++wr) {
            int wk = p0 + wr - 4;
            float v0 = 0.f, v1 = 0.f;
            if (wk >= 0 && wk < W_) { v0 = xr[wk * C_ + l]; v1 = xr[wk * C_ + l + 64]; }
#pragma unroll
            for (int pi = 0; pi < 8; ++pi) {
                int k = wr - pi;
                if (k >= 0 && k < 9) part[pi] += v0 * w1a[k] + v1 * w1b[k];
            }
        }
#pragma unroll
        for (int pi = 0; pi < 8; ++pi) {
            float v = part[pi];
#pragma unroll
            for (int off = 32; off > 0; off >>= 1) v += __shfl_down(v, off, 64);
            if (l == 0) c1x[(size_t)bid * W_ + p0 + pi] = v + b1v;
        }
    }
}

// ---------------------------------------------------------------- K12 (fused K1+K2)
// Round-5: xb round-trip ELIMINATED. The fp32 z-row is read directly from x
// (clean, read-only lines: no cross-XCD dirty-probe traffic, L3-resident) and
// reg-staged with inline f2bf into p_lds (coalesced 1KB/instr bursts; LDS bits
// identical to the old xb path -> absmax preserved). nt stores reverted (R4:
// WRITE went UP). z and p share the LDS buffer in place (verified R3).
// sc[w] from c1x; GEMM1: v = relu(z@W2 + sc*cs2 + b2) [rank-1 sc fold];
// p[w+1] = z[w+1] + sc[w+1] + v[w]; GEMM2 on p; q epilogue as before.
__global__ __launch_bounds__(256, 2) void k12_fused(
    const float* __restrict__ x, const float* __restrict__ b2,
    const float* __restrict__ c1x_all, const float* __restrict__ s1,
    const unsigned short* __restrict__ w2t, const float* __restrict__ cs2,
    float* __restrict__ qout) {
    __shared__ unsigned short p_lds[W_ * PS];   // 69632 B (z, then p, in place)
    __shared__ float sc[W_];                    // 1024 B
    int bid = blockIdx.x;            // row index b*H + i
    int b = bid >> 7, i = bid & 127;
    int tid = threadIdx.x;
    const float* c1 = c1x_all + (size_t)b * H_ * W_;

    int rowY;
    if (i == H_ - 1) rowY = H_ - 1;
    else if (i <= H_ - 3) rowY = (i - 1) & (H_ - 1);
    else rowY = H_ - 2;

    const float* zrow = x + ((size_t)b * H_ + rowY) * (W_ * C_);
    float* qrow = qout + (size_t)bid * (W_ * C_);

    // ---- phase -1: reg-stage z row (fp32 -> bf16) into p_lds.
    // Iteration i: 64 lanes read 1KB contiguous (f32x4/lane, coalesced).
    // Float idx g = it*1024 + tid*4; row = g>>7 (never split: 4|128);
    // dest = p_lds[row*PS + (g&127)] as u16x4 (8B aligned; 2-way banks = free).
    {
        const f32x4* z4 = (const f32x4*)zrow;
#pragma unroll 4
        for (int it = 0; it < 32; ++it) {
            int g = it * 1024 + tid * 4;
            f32x4 v = z4[g >> 2];
            u16x4 o;
#pragma unroll
            for (int j = 0; j < 4; ++j) o[j] = f2bf(v[j]);
            int row = g >> 7, col = g & 127;
            *(u16x4*)(&p_lds[row * PS + col]) = o;
        }
    }

    {   // phase 0: per-w scalar sc
        int w = tid;
        float scv;
        if (i == H_ - 1) {
            scv = relu(c1[(H_ - 2) * W_ + w]);
        } else {
            int iu = (i <= H_ - 3) ? i : (H_ - 1);
            float cu = c1[iu * W_ + w];
            if (iu >= 1) {
                const float* tp = c1 + (iu - 1) * W_;
#pragma unroll
                for (int k = 0; k < 9; ++k) {
                    int wk = w + k - 4;
                    if (wk >= 0 && wk < W_) cu += relu(tp[wk]) * s1[k];
                }
            }
            float tY = (rowY >= 1) ? relu(c1[(rowY - 1) * W_ + w]) : 0.f;
            scv = tY + relu(cu);
        }
        sc[w] = scv;
    }
    __syncthreads();   // staged z visible; sc visible

    int wv = tid >> 6, l = tid & 63, q = l >> 4, l15 = l & 15;
    int m0 = wv * 64;

    // epilogue constants: 4 consecutive channels per thread per nt
    f32x4 b2v4[8], cs2v4[8];
#pragma unroll
    for (int nt = 0; nt < 8; ++nt) {
        int d0 = nt * 16 + q * 4;
        b2v4[nt] = *(const f32x4*)(b2 + d0);
        cs2v4[nt] = *(const f32x4*)(cs2 + d0);
    }

    f32x4 acc[4][8];
#pragma unroll
    for (int mt = 0; mt < 4; ++mt)
#pragma unroll
        for (int nt = 0; nt < 8; ++nt) acc[mt][nt] = (f32x4){0.f, 0.f, 0.f, 0.f};

    // ---- GEMM1: A-op = w2t frag, B-op = z frag (bf16, LDS)  -> D[d, w]
#pragma unroll
    for (int kk = 0; kk < C_; kk += 32) {
        s16x8 af[4], bfr[8];
#pragma unroll
        for (int mt = 0; mt < 4; ++mt) {
            int w = m0 + mt * 16 + l15;
            af[mt] = *(const s16x8*)(&p_lds[w * PS + kk + q * 8]);   // staged z
        }
#pragma unroll
        for (int nt = 0; nt < 8; ++nt)
            bfr[nt] = *(const s16x8*)(w2t + (nt * 16 + l15) * C_ + kk + q * 8);
#pragma unroll
        for (int mt = 0; mt < 4; ++mt)
#pragma unroll
            for (int nt = 0; nt < 8; ++nt)
                acc[mt][nt] = __builtin_amdgcn_mfma_f32_16x16x32_bf16(bfr[nt], af[mt], acc[mt][nt], 0, 0, 0);
    }
    __syncthreads();   // all waves done reading z before in-place p overwrite

    // ---- epilogue 1: p[w+1] = z[w+1] + sc[w+1] + v[w]  (in-place LDS update)
    // thread's read slot z[w+1,d0..d0+3] is exactly the slot it overwrites.
#pragma unroll
    for (int mt = 0; mt < 4; ++mt) {
        int w = m0 + mt * 16 + l15;
        if (w < W_ - 1) {
            float scw = sc[w], scw1 = sc[w + 1];
#pragma unroll
            for (int nt = 0; nt < 8; ++nt) {
                int d0 = nt * 16 + q * 4;
                u16x4 zv4 = *(const u16x4*)(&p_lds[(w + 1) * PS + d0]);
                u16x4 pb;
                f32x4 pf;
#pragma unroll
                for (int r = 0; r < 4; ++r) {
                    float v = relu(acc[mt][nt][r] + scw * cs2v4[nt][r] + b2v4[nt][r]);
                    float p = bf2f(zv4[r]) + scw1 + v;
                    pf[r] = p;
                    pb[r] = f2bf(p);
                }
                *(u16x4*)(&p_lds[(w + 1) * PS + d0]) = pb;       // ds_write_b64
                if (w == W_ - 2)                                  // q[W-1] = p[W-1], exact fp32
                    *(f32x4*)(qrow + (W_ - 1) * C_ + d0) = pf;
            }
        }
    }
    // p[0] = z[0] + sc[0]: row 0 still holds z[0]; same-thread read-then-write
    if (tid < C_) {
        float z0 = bf2f(p_lds[tid]);
        p_lds[tid] = f2bf(z0 + sc[0]);
    }
    __syncthreads();

    // ---- GEMM2: A-op = w2t frag, B-op = p frag (bf16, LDS)
#pragma unroll
    for (int mt = 0; mt < 4; ++mt)
#pragma unroll
        for (int nt = 0; nt < 8; ++nt) acc[mt][nt] = (f32x4){0.f, 0.f, 0.f, 0.f};
#pragma unroll
    for (int kk = 0; kk < C_; kk += 32) {
        s16x8 af[4], bfr[8];
#pragma unroll
        for (int mt = 0; mt < 4; ++mt) {
            int w = m0 + mt * 16 + l15;
            af[mt] = *(const s16x8*)(&p_lds[w * PS + kk + q * 8]);
        }
#pragma unroll
        for (int nt = 0; nt < 8; ++nt)
            bfr[nt] = *(const s16x8*)(w2t + (nt * 16 + l15) * C_ + kk + q * 8);
#pragma unroll
        for (int mt = 0; mt < 4; ++mt)
#pragma unroll
            for (int nt = 0; nt < 8; ++nt)
                acc[mt][nt] = __builtin_amdgcn_mfma_f32_16x16x32_bf16(bfr[nt], af[mt], acc[mt][nt], 0, 0, 0);
    }
    // ---- epilogue 2: q stores (f32x4, 16B per lane)
#pragma unroll
    for (int mt = 0; mt < 4; ++mt) {
        int w = m0 + mt * 16 + l15;
        if (w == W_ - 2) continue;       // r[W-2] unused; q[W-1] already stored
        int wsrc = (w - 1) & (W_ - 1);
        int wd = (w <= W_ - 3) ? w : (W_ - 2);   // w==W-1 -> q[W-2] = r[W-1] + p[W-2]
#pragma unroll
        for (int nt = 0; nt < 8; ++nt) {
            int d0 = nt * 16 + q * 4;
            u16x4 pv4 = *(const u16x4*)(&p_lds[wsrc * PS + d0]);  // ds_read_b64
            f32x4 o;
#pragma unroll
            for (int r = 0; r < 4; ++r) {
                float rr = relu(acc[mt][nt][r] + b2v4[nt][r]);
                o[r] = rr + bf2f(pv4[r]);
            }
            *(f32x4*)(qrow + wd * C_ + d0) = o;
        }
    }
}

extern "C" void kernel_launch(void* const* d_in, const int* in_sizes, int n_in,
                              void* d_out, int out_size, void* d_ws, size_t ws_size,
                              hipStream_t stream) {
    const float* x  = (const float*)d_in[0];
    const float* w1 = (const float*)d_in[1];
    const float* b1 = (const float*)d_in[2];
    const float* w2 = (const float*)d_in[3];
    const float* b2 = (const float*)d_in[4];
    float* out = (float*)d_out;

    float* wsf = (float*)d_ws;
    // ws layout (floats): c1x[262144] | s1[16] | w2t[8192] | cs2[128]
    float* c1x = wsf;
    float* s1  = wsf + 262144;
    unsigned short* w2t = (unsigned short*)(wsf + 262160);
    float* cs2 = wsf + 270352;

    k0_conv1<<<B_ * H_ + (C_ * D_) / 256, 256, 0, stream>>>(x, w1, b1, w2, c1x, s1, w2t, cs2);
    k12_fused<<<B_ * H_, 256, 0, stream>>>(x, b2, c1x, s1, w2t, cs2, out);
}